// Round 9
// baseline (111.188 us; speedup 1.0000x reference)
//
#include <hip/hip_runtime.h>

#define M 32                        // reflection coeffs
#define NC 33                       // floats per row
#define TPB 64                      // ONE wave per block
#define ROWS 128                    // rows per tile (2 per thread: t and t+64)
#define FPB (ROWS * NC)             // 4224 floats = 16896 B per tile
#define V4R 16                      // f4 store rounds: 16*64*4 = 4096 floats
#define TAILF 4096                  // last 128 floats
#define NBLOCKS 1024                // 4 resident blocks/CU (LDS: 2*16.9KB each)
#define DMA_N 18                    // vmem ops per tile DMA (16 x16B + 2 x4B)

typedef float f4 __attribute__((ext_vector_type(4)));

// ---- async global->LDS DMA: lds dest is wave-uniform base + lane*width ----
__device__ __forceinline__ void dma16(const float* g, float* l) {
    __builtin_amdgcn_global_load_lds(
        (const __attribute__((address_space(1))) unsigned int*)g,
        (__attribute__((address_space(3))) unsigned int*)l, 16, 0, 0);
}
__device__ __forceinline__ void dma4(const float* g, float* l) {
    __builtin_amdgcn_global_load_lds(
        (const __attribute__((address_space(1))) unsigned int*)g,
        (__attribute__((address_space(3))) unsigned int*)l, 4, 0, 0);
}

// One full tile: 18 DMA ops per wave. LDS layout linear (matches lane*width).
__device__ __forceinline__ void issue_tile_dma(const float* __restrict__ src,
                                               float* __restrict__ lbuf, int lane) {
#pragma unroll
    for (int k = 0; k < 16; ++k)
        dma16(src + k * 256 + lane * 4, lbuf + k * 256);    // 64 lanes x 16B = 1KB
#pragma unroll
    for (int r = 0; r < 2; ++r)
        dma4(src + TAILF + r * 64 + lane, lbuf + TAILF + r * 64);
}

// Packed Levinson: thread t owns rows t (.x) and t+64 (.y).
// Row bases 33t and 33t+2112 (2112%32==0): all b32 LDS access spreads over all
// 32 banks (2 lanes/bank = free). Exact IEEE div only (R2 lesson).
typedef float f2 __attribute__((ext_vector_type(2)));
__device__ __forceinline__ void levinson2(float* __restrict__ lds, int t) {
    const int rb0 = t * NC;
    const int rb1 = t * NC + 64 * NC;
    f2 ar[M];
#pragma unroll
    for (int j = 0; j < M; ++j) {
        ar[j].x = lds[rb0 + 1 + j];
        ar[j].y = lds[rb1 + 1 + j];
    }
#pragma unroll
    for (int m = M - 1; m >= 1; --m) {
        f2 km = ar[m];
        lds[rb0 + m + 1] = km.x;                 // out[..., m+1]
        lds[rb1 + m + 1] = km.y;
        f2 z = 1.0f - km * km;
        f2 r;
        r.x = 1.0f / z.x;                        // exact IEEE div, 2 indep chains
        r.y = 1.0f / z.y;
        const int h = m >> 1;
#pragma unroll
        for (int j = 0; j < h; ++j) {            // packed symmetric pair update
            f2 x = ar[j], y = ar[m - 1 - j];
            ar[j]         = (x - km * y) * r;
            ar[m - 1 - j] = (y - km * x) * r;
        }
        if (m & 1) ar[h] = (ar[h] - km * ar[h]) * r;
    }
    lds[rb0 + 1] = ar[0].x;
    lds[rb1 + 1] = ar[0].y;
    // lds[rb0+0]/lds[rb1+0] still hold K untouched.
}

__device__ __forceinline__ void store_tile_nt(float* __restrict__ dst,
                                              const float* __restrict__ lds, int t) {
    const f4* l4 = (const f4*)lds;
#pragma unroll
    for (int k = 0; k < V4R; ++k) {
        f4 v = l4[t + k * TPB];
        __builtin_nontemporal_store(v, (f4*)dst + t + k * TPB);
    }
    __builtin_nontemporal_store(lds[TAILF + t],       dst + TAILF + t);
    __builtin_nontemporal_store(lds[TAILF + TPB + t], dst + TAILF + TPB + t);
}

// guarded slow path for a (possibly partial) tile — safe in 1-wave blocks
__device__ __forceinline__ void process_tile_guarded(float* __restrict__ lds,
                                                     const float* __restrict__ a,
                                                     float* __restrict__ out,
                                                     long long base, long long limit, int t) {
    for (int k = 0; k < 66; ++k) {
        int g = t + k * TPB;
        long long ga = base + g;
        lds[g] = (ga < limit) ? a[ga] : 0.0f;
    }
    __syncthreads();
    levinson2(lds, t);
    __syncthreads();
    for (int k = 0; k < 66; ++k) {
        int g = t + k * TPB;
        long long ga = base + g;
        if (ga < limit) out[ga] = lds[g];
    }
    __syncthreads();
}

__global__ __launch_bounds__(TPB, 1)
void lpc_to_parcor_kernel(const float* __restrict__ a,
                          float* __restrict__ out,
                          long long nrows, long long tiles_per_block) {
    __shared__ float lds[2 * FPB];               // double buffer, 33792 B
    const int t = threadIdx.x;
    const long long limit = nrows * NC;
    const long long ntiles = (nrows + ROWS - 1) / ROWS;
    const long long nfull  = nrows / ROWS;

    long long t0 = (long long)blockIdx.x * tiles_per_block;
    long long t1 = t0 + tiles_per_block; if (t1 > ntiles) t1 = ntiles;
    if (t0 >= t1) return;
    long long fend = (t1 < nfull) ? t1 : nfull;  // full tiles in [t0, fend)

    if (t0 < fend) {
        issue_tile_dma(a + t0 * FPB, lds, t);    // prologue -> buf0

        for (long long ti = t0; ti < fend; ++ti) {
            float* cur = lds + ((int)((ti - t0) & 1)) * FPB;
            float* nxt = lds + ((int)((ti - t0 + 1) & 1)) * FPB;

            // Drain DMA(cur). Steady state: outstanding = [old stores<=18]
            // [DMA(cur) 18]; vmcnt(18) leaves at most the newest 18 (never
            // DMA(cur), which is older than the previous tile's stores? No:
            // DMA(cur) issued BEFORE stores(prev), so vmcnt(18) drains it.)
            if (ti == t0) asm volatile("s_waitcnt vmcnt(0)"  ::: "memory");
            else          asm volatile("s_waitcnt vmcnt(18)" ::: "memory");

            // Issue next tile's DMA now; it stays in flight under compute.
            // Safe vs stores(prev) reading nxt: those ds_reads completed
            // before their store instrs issued (program order + lgkmcnt).
            if (ti + 1 < fend) issue_tile_dma(a + (ti + 1) * FPB, nxt, t);

            levinson2(cur, t);                   // ~1100 VALU, hides DMA(next)

            store_tile_nt(out + ti * FPB, cur, t);   // 18 nt stores, no wait
        }
    }
    // guarded tail tiles (none for 2048x1024 rows; kept for generality)
    for (long long ti = (t0 > nfull ? t0 : nfull); ti < t1; ++ti) {
        asm volatile("s_waitcnt vmcnt(0)" ::: "memory");
        __syncthreads();
        process_tile_guarded(lds, a, out, ti * FPB, limit, t);
    }
}

extern "C" void kernel_launch(void* const* d_in, const int* in_sizes, int n_in,
                              void* d_out, int out_size, void* d_ws, size_t ws_size,
                              hipStream_t stream) {
    const float* a = (const float*)d_in[0];
    float* out = (float*)d_out;
    long long nrows = (long long)in_sizes[0] / NC;
    long long ntiles = (nrows + ROWS - 1) / ROWS;
    long long blocks = (ntiles < NBLOCKS) ? ntiles : NBLOCKS;
    long long tpb_tiles = (ntiles + blocks - 1) / blocks;
    lpc_to_parcor_kernel<<<(int)blocks, TPB, 0, stream>>>(a, out, nrows, tpb_tiles);
}